// Round 1
// baseline (241.283 us; speedup 1.0000x reference)
//
#include <hip/hip_runtime.h>
#include <stdint.h>

typedef float f32x16 __attribute__((ext_vector_type(16)));
typedef short bf16x8 __attribute__((ext_vector_type(8)));
typedef uint32_t u32;

#define T_LEN 8192
#define E_DIM 64
#define WSZ   128
#define NWIN  64
#define NBH   32

union Frag { u32 w[4]; bf16x8 v; };

__device__ __forceinline__ u32 pkbf(float a, float b) {
    u32 r;
    asm("v_cvt_pk_bf16_f32 %0, %1, %2" : "=v"(r) : "v"(a), "v"(b));
    return r;
}

// K tile: bf16 [256 keys][64 e], row = 128B. XOR-swizzle (bijective, same fn for
// read+write): spreads the otherwise same-bank 128B-stride column reads.
__device__ __forceinline__ u32 kaddr(u32 key, u32 bir) {
    return (key * 128u + bir) ^ ((key & 15u) << 4);
}
// V^T tile: bf16 [64 d][256 keys], row = 512B, swizzle within row.
__device__ __forceinline__ u32 vtaddr(u32 d, u32 bir) {
    return 32768u + d * 512u + (bir ^ ((d & 31u) << 4));
}

__global__ __launch_bounds__(256, 2)
void lattn_kernel(const float* __restrict__ qg, const float* __restrict__ kg,
                  const float* __restrict__ vg, float* __restrict__ outg) {
    __shared__ __align__(16) char lds[65536];

    const int tid  = threadIdx.x;
    const int lane = tid & 63;
    const int wid  = tid >> 6;   // wave 0..3, owns queries [wid*32, wid*32+32)
    const int h    = lane >> 5;  // lane half (MFMA k-group)
    const int ql   = lane & 31;  // this lane's query column / d column

    // XCD-contiguous window mapping: consecutive windows -> same XCD L2
    const int bid = blockIdx.x;
    const int swz = ((bid & 7) << 8) | (bid >> 3);
    const int bh  = swz >> 6;
    const int w   = swz & 63;

    const size_t qrow0 = (size_t)bh * T_LEN + (size_t)w * WSZ;

    // ---- Q fragments (B operand of S^T = K*Q^T), straight from global ----
    Frag qf[4];
    {
        const float* qp = qg + (qrow0 + (size_t)(wid * 32 + ql)) * E_DIM;
#pragma unroll
        for (int ks = 0; ks < 4; ++ks) {
            float4 a = *(const float4*)(qp + ks * 16 + h * 8);
            float4 b = *(const float4*)(qp + ks * 16 + h * 8 + 4);
            qf[ks].w[0] = pkbf(a.x, a.y);
            qf[ks].w[1] = pkbf(a.z, a.w);
            qf[ks].w[2] = pkbf(b.x, b.y);
            qf[ks].w[3] = pkbf(b.z, b.w);
        }
    }

    // ---- stage K and V^T (keys 0..255 = prev window ++ current window) ----
    {
        const int krow0 = bh * T_LEN + (w - 1) * WSZ; // row of key 0 (may be <0 for w=0)
#pragma unroll
        for (int i = 0; i < 16; ++i) {
            const int f   = i * 256 + tid;  // wave reads 4 consecutive rows (1KB) per iter
            const int key = f >> 4;
            const int c   = f & 15;
            float4 kv = make_float4(0.f, 0.f, 0.f, 0.f);
            float4 vv = make_float4(0.f, 0.f, 0.f, 0.f);
            if ((w > 0) || (key >= 128)) {     // zero-fill pad keys (avoids NaN*0 in PV)
                const size_t off = ((size_t)(krow0 + key)) * E_DIM + (size_t)(c * 4);
                kv = *(const float4*)(kg + off);
                vv = *(const float4*)(vg + off);
            }
            const u32 k0 = pkbf(kv.x, kv.y), k1 = pkbf(kv.z, kv.w);
            *(uint2*)(lds + kaddr((u32)key, (u32)c * 8u)) = make_uint2(k0, k1);
            const u32 v0 = pkbf(vv.x, vv.y), v1 = pkbf(vv.z, vv.w);
            *(uint16_t*)(lds + vtaddr((u32)(4 * c + 0), 2u * (u32)key)) = (uint16_t)(v0 & 0xffffu);
            *(uint16_t*)(lds + vtaddr((u32)(4 * c + 1), 2u * (u32)key)) = (uint16_t)(v0 >> 16);
            *(uint16_t*)(lds + vtaddr((u32)(4 * c + 2), 2u * (u32)key)) = (uint16_t)(v1 & 0xffffu);
            *(uint16_t*)(lds + vtaddr((u32)(4 * c + 3), 2u * (u32)key)) = (uint16_t)(v1 >> 16);
        }
    }
    __syncthreads();

    // ---- S^T = K * Q^T : lane holds S[key][q=ql] for 128 of the 256 keys ----
    f32x16 acc[8];
#pragma unroll
    for (int kf = 0; kf < 8; ++kf)
#pragma unroll
        for (int r = 0; r < 16; ++r) acc[kf][r] = 0.f;

#pragma unroll
    for (int kf = 0; kf < 8; ++kf) {
#pragma unroll
        for (int ks = 0; ks < 4; ++ks) {
            const bf16x8 af = *(const bf16x8*)(lds + kaddr((u32)(32 * kf + ql),
                                                           (u32)(32 * ks + 16 * h)));
            acc[kf] = __builtin_amdgcn_mfma_f32_32x32x16_bf16(af, qf[ks].v, acc[kf], 0, 0, 0);
        }
    }

    // ---- mask + softmax (partner lane^32 holds the other half of the keys) ----
    const int qpos = wid * 32 + ql;           // query pos within window
    float m = -1e30f;
#pragma unroll
    for (int kf = 0; kf < 8; ++kf) {
#pragma unroll
        for (int r = 0; r < 16; ++r) {
            const int key = 32 * kf + (r & 3) + 8 * (r >> 2) + 4 * h;  // 0..255
            // key global offset = key - 128 relative to window start
            const bool vis = ((key - 128) <= qpos) && ((w > 0) || (key >= 128));
            const float sv = vis ? acc[kf][r] * 0.125f : -1e30f;
            acc[kf][r] = sv;
            m = fmaxf(m, sv);
        }
    }
    m = fmaxf(m, __shfl_xor(m, 32));
    float den = 0.f;
#pragma unroll
    for (int kf = 0; kf < 8; ++kf) {
#pragma unroll
        for (int r = 0; r < 16; ++r) {
            const float p = __expf(acc[kf][r] - m);
            acc[kf][r] = p;
            den += p;
        }
    }
    den += __shfl_xor(den, 32);
    const float invd = 1.f / den;

    // ---- O = P * V : P->bf16 A-operands via cvt_pk + lane^32 exchange ----
    f32x16 oa[2];
#pragma unroll
    for (int r = 0; r < 16; ++r) { oa[0][r] = 0.f; oa[1][r] = 0.f; }

#pragma unroll
    for (int kf = 0; kf < 8; ++kf) {
        u32 W[8];
#pragma unroll
        for (int j = 0; j < 8; ++j) W[j] = pkbf(acc[kf][2 * j], acc[kf][2 * j + 1]);
#pragma unroll
        for (int hi = 0; hi < 2; ++hi) {
            const u32 w0 = W[4 * hi + 0], w1 = W[4 * hi + 1];
            const u32 w2 = W[4 * hi + 2], w3 = W[4 * hi + 3];
            const u32 y0 = (u32)__shfl_xor((int)w0, 32);
            const u32 y1 = (u32)__shfl_xor((int)w1, 32);
            const u32 y2 = (u32)__shfl_xor((int)w2, 32);
            const u32 y3 = (u32)__shfl_xor((int)w3, 32);
            Frag au;
            // dest h=0: elems0-3 = own regs 8hi+0..3, elems4-7 = partner regs 8hi+0..3
            // dest h=1: elems0-3 = partner regs 8hi+4..7, elems4-7 = own regs 8hi+4..7
            au.w[0] = h ? y2 : w0;
            au.w[1] = h ? y3 : w1;
            au.w[2] = h ? w2 : y0;
            au.w[3] = h ? w3 : y1;
            const int ks = 2 * kf + hi;
#pragma unroll
            for (int df = 0; df < 2; ++df) {
                const bf16x8 bv = *(const bf16x8*)(lds + vtaddr((u32)(32 * df + ql),
                                                                (u32)(32 * ks + 16 * h)));
                oa[df] = __builtin_amdgcn_mfma_f32_32x32x16_bf16(au.v, bv, oa[df], 0, 0, 0);
            }
        }
    }

    // ---- normalize rows + store (row of D = query, col = d) ----
    float* ob = outg + (qrow0 + (size_t)(wid * 32)) * E_DIM;
#pragma unroll
    for (int r = 0; r < 16; ++r) {
        const int rowq = (r & 3) + 8 * (r >> 2) + 4 * h;
        const float dn = __shfl(invd, rowq);   // lane rowq holds 1/den for query rowq
        ob[(size_t)rowq * E_DIM + ql]      = oa[0][r] * dn;
        ob[(size_t)rowq * E_DIM + 32 + ql] = oa[1][r] * dn;
    }
}

extern "C" void kernel_launch(void* const* d_in, const int* in_sizes, int n_in,
                              void* d_out, int out_size, void* d_ws, size_t ws_size,
                              hipStream_t stream) {
    const float* q = (const float*)d_in[0];
    const float* k = (const float*)d_in[1];
    const float* v = (const float*)d_in[2];
    float* out = (float*)d_out;
    lattn_kernel<<<dim3(NBH * NWIN), dim3(256), 0, stream>>>(q, k, v, out);
}